// Round 17
// baseline (60.385 us; speedup 1.0000x reference)
//
#include <hip/hip_runtime.h>
#include <math.h>

#define FRAME_LEN 512
#define HOP       256
#define NFREQ     257
#define NBATCH    64
#define NSAMP     160000
#define NSQ       40000        // samples per residue per batch
#define TFRAMES   624
#define EPS       1.1920928955078125e-07f

#define MT 128                 // frames per tile; 312 M-tiles
#define FT 32                  // freq bins per tile; 3 f-tiles (f 0..64 pad 96)
#define BK 64                  // k' chunk per stage
#define RS 2560000             // shorts per residue array (64*40000)
#define TBLKS 96
#define XBLKS 2500             // x blocks: 16 f32/thread

#define ASZ (MT * BK)          // shorts per A buffer (8192)
// WT fragment-order tables: [res 4][cs 2][tileF 3][nf 2][kc 4][512 shorts]
#define WT_RES   24576
#define WT_CS    12288
#define WT_TILEF 4096
#define WT_NF    2048
#define WT_KC    512
#define WT_TOTAL (4 * WT_RES)

typedef __attribute__((ext_vector_type(8))) short short8;   // 8 bf16
typedef __attribute__((ext_vector_type(4))) float f32x4;    // MFMA acc

static __device__ __forceinline__ unsigned int f2bf(float f) {
    unsigned int u = __float_as_uint(f);
    return (u + 0x7fffu + ((u >> 16) & 1u)) >> 16;          // RNE to bf16
}
static __device__ __forceinline__ void gload_lds16(const void* g, void* l) {
    __builtin_amdgcn_global_load_lds(
        (const __attribute__((address_space(1))) void*)g,
        (__attribute__((address_space(3))) void*)l, 16, 0, 0);
}

// ---- prep: fragment-order tables + x de-interleaved mod 4 -> xq[r] ---------
__global__ __launch_bounds__(256) void prep(const float* __restrict__ x,
                                            unsigned short* __restrict__ xq,
                                            unsigned short* __restrict__ Wt) {
    if (blockIdx.x < TBLKS) {                   // tables; f<=64 live, rest 0
        const int f = blockIdx.x;               // 0..95
        const int tileF = f >> 5, nf = (f >> 4) & 1, lrow = f & 15;
        #pragma unroll
        for (int h = 0; h < 2; h++) {
            const int n = threadIdx.x + h * 256;        // 0..511
            unsigned short cb = 0, sb = 0;
            if (f <= 64) {
                float w = 0.5f * (1.0f - cosf(2.0f * (float)M_PI * (float)n / (float)FRAME_LEN));
                float ang = (float)((f * n) & (FRAME_LEN - 1)) * (2.0f * (float)M_PI / (float)FRAME_LEN);
                float sv, cv;
                sincosf(ang, &sv, &cv);
                cb = (unsigned short)f2bf(cv * w);
                sb = (unsigned short)f2bf(sv * w);      // i = +sin convention
            }
            const int r = n & 3, q = n >> 2;            // residue, k' 0..127
            const int kc = q >> 5, rem = q & 31;
            const size_t lane_off = (size_t)lrow * 32 + rem;
            const size_t base = (size_t)r * WT_RES + tileF * WT_TILEF
                              + nf * WT_NF + kc * WT_KC + lane_off;
            Wt[base] = cb;                      // cs = 0 (cos)
            Wt[base + WT_CS] = sb;              // cs = 1 (sin)
        }
    } else {                                    // 16 f32/thread, mod-4 split
        const int i = (blockIdx.x - TBLKS) * 256 + threadIdx.x;
        const int g = i * 16;
        const int b = g / NSAMP;
        const int s = g - b * NSAMP;            // 160000%16==0: one batch
        const float4* src = (const float4*)(x + (size_t)b * NSAMP + s);
        const float4 v0 = src[0], v1 = src[1], v2 = src[2], v3 = src[3];
        const size_t o = (size_t)b * NSQ + (s >> 2);
        uint2 p;
        p.x = f2bf(v0.x) | (f2bf(v1.x) << 16);
        p.y = f2bf(v2.x) | (f2bf(v3.x) << 16);
        *(uint2*)(xq + 0 * (size_t)RS + o) = p;
        p.x = f2bf(v0.y) | (f2bf(v1.y) << 16);
        p.y = f2bf(v2.y) | (f2bf(v3.y) << 16);
        *(uint2*)(xq + 1 * (size_t)RS + o) = p;
        p.x = f2bf(v0.z) | (f2bf(v1.z) << 16);
        p.y = f2bf(v2.z) | (f2bf(v3.z) << 16);
        *(uint2*)(xq + 2 * (size_t)RS + o) = p;
        p.x = f2bf(v0.w) | (f2bf(v1.w) << 16);
        p.y = f2bf(v2.w) | (f2bf(v3.w) << 16);
        *(uint2*)(xq + 3 * (size_t)RS + o) = p;
    }
}

// ---- stft: radix-4, A via LDS dbuf, B fragments direct from global ---------
__global__ __launch_bounds__(256) void stft_mfma(
    const unsigned short* __restrict__ xq, const unsigned short* __restrict__ Wt,
    float* __restrict__ mag)
{
    __shared__ unsigned short As[2][MT][BK];    // 32 KB only (no B in LDS)

    const int tid = threadIdx.x;
    // XCD swizzle: nwg=936=8*117; 3 consecutive logicals share an A-tile.
    const int logical = ((int)blockIdx.x & 7) * 117 + ((int)blockIdx.x >> 3);
    const int tileM = logical / 3;              // 0..311
    const int tileF = logical % 3;              // 0..2
    const int wid = tid >> 6;
    const int lane = tid & 63;
    const int lrow = lane & 15;
    const int lhi = lane >> 4;

    unsigned short* AsB = &As[0][0][0];

    // A staging sources (XOR chunk swizzle on SOURCE; dest linear)
    const unsigned short* pA[4];
    #pragma unroll
    for (int j = 0; j < 4; j++) {
        int idx = wid * 4 + j;                  // 0..15, 8 rows each
        int row = idx * 8 + (lane >> 3);
        int m = tileM * MT + row;               // < 39936 exact
        int b = m / TFRAMES;
        int t = m - b * TFRAMES;
        int chunk = (lane & 7) ^ (row & 7);
        pA[j] = xq + (size_t)b * NSQ + t * (HOP / 4) + chunk * 8;
    }
    // B per-lane fragment base (res/cs/nf/kc fold into compile-time offsets)
    const unsigned short* pB = Wt + tileF * WT_TILEF + lrow * 32 + lhi * 8;

    f32x4 aC[4][2][2] = {};                     // [residue][mf][nf]
    f32x4 aS[4][2][2] = {};

    // ---- prologue: stage A(residue 0, kc 0) into buf 0
    #pragma unroll
    for (int j = 0; j < 4; j++)
        gload_lds16(pA[j], AsB + (wid * 4 + j) * 512);
    __syncthreads();

    int buf = 0;
    #pragma unroll
    for (int it = 0; it < 8; it++) {
        const int R = it >> 1;                  // residue (compile-time)
        const int half = it & 1;                // k'-half within residue
        // ---- stage next A chunk into other buffer
        if (it < 7) {
            const int Rn = (it + 1) >> 1;
            const int kn = ((it + 1) & 1) * BK;
            const size_t aoff = (size_t)Rn * RS + kn;
            #pragma unroll
            for (int j = 0; j < 4; j++)
                gload_lds16(pA[j] + aoff, AsB + (buf ^ 1) * ASZ + (wid * 4 + j) * 512);
        }
        // ---- compute: 2 K=32 sub-steps; B straight from global (L1-hot)
        #pragma unroll
        for (int ks = 0; ks < 2; ks++) {
            const int kc = half * 2 + ks;       // compile-time
            short8 a[2], bc[2], bsn[2];
            const int c = (ks * 4 + lhi) ^ (lrow & 7);
            #pragma unroll
            for (int mf = 0; mf < 2; mf++)
                a[mf] = *(const short8*)(AsB + buf * ASZ +
                    (wid * 32 + mf * 16 + lrow) * BK + c * 8);
            #pragma unroll
            for (int nf = 0; nf < 2; nf++) {
                bc[nf]  = *(const short8*)(pB + (size_t)R * WT_RES +
                    nf * WT_NF + kc * WT_KC);
                bsn[nf] = *(const short8*)(pB + (size_t)R * WT_RES + WT_CS +
                    nf * WT_NF + kc * WT_KC);
            }
            #pragma unroll
            for (int mf = 0; mf < 2; mf++) {
                #pragma unroll
                for (int nf = 0; nf < 2; nf++) {
                    aC[R][mf][nf] = __builtin_amdgcn_mfma_f32_16x16x32_bf16(
                        a[mf], bc[nf], aC[R][mf][nf], 0, 0, 0);
                    aS[R][mf][nf] = __builtin_amdgcn_mfma_f32_16x16x32_bf16(
                        a[mf], bsn[nf], aS[R][mf][nf], 0, 0, 0);
                }
            }
        }
        __syncthreads();                        // next A buffer landed
        buf ^= 1;
    }

    // ---- epilogue: 4 bins per f<=64 via quarter-period sign combos
    #pragma unroll
    for (int mf = 0; mf < 2; mf++) {
        int m0 = tileM * MT + wid * 32 + mf * 16 + lhi * 4;
        int b = m0 / TFRAMES;
        int t = m0 - b * TFRAMES;               // %4==0, run stays in batch
        float* magb = mag + (size_t)b * NFREQ * TFRAMES + t;
        #pragma unroll
        for (int nf = 0; nf < 2; nf++) {
            int f = tileF * FT + nf * 16 + lrow;    // 0..95
            float4 o1, o2, o3, o4;
            #pragma unroll
            for (int q = 0; q < 4; q++) {
                const float C0 = aC[0][mf][nf][q], C1 = aC[1][mf][nf][q];
                const float C2 = aC[2][mf][nf][q], C3 = aC[3][mf][nf][q];
                const float S0 = aS[0][mf][nf][q], S1 = aS[1][mf][nf][q];
                const float S2 = aS[2][mf][nf][q], S3 = aS[3][mf][nf][q];
                float r, i2;
                r = (C0 + C2) + (C1 + C3); i2 = (S0 + S2) + (S1 + S3);  // f
                (&o1.x)[q] = sqrtf(r * r + i2 * i2);
                r = (C0 - C2) + (S1 - S3); i2 = (C1 - C3) - (S0 - S2);  // 128-f
                (&o2.x)[q] = sqrtf(r * r + i2 * i2);
                r = (C0 - C2) - (S1 - S3); i2 = (C1 - C3) + (S0 - S2);  // 128+f
                (&o3.x)[q] = sqrtf(r * r + i2 * i2);
                r = (C0 + C2) - (C1 + C3); i2 = (S1 + S3) - (S0 + S2);  // 256-f
                (&o4.x)[q] = sqrtf(r * r + i2 * i2);
            }
            if (f <= 64)           *(float4*)(magb + (size_t)f * TFRAMES) = o1;
            if (f <= 63)           *(float4*)(magb + (size_t)(128 - f) * TFRAMES) = o2;
            if (f >= 1 && f <= 64) *(float4*)(magb + (size_t)(128 + f) * TFRAMES) = o3;
            if (f <= 63)           *(float4*)(magb + (size_t)(256 - f) * TFRAMES) = o4;
        }
    }
}

// ------------------------------------------- normalize: warp-per-row, f4 ----
__global__ __launch_bounds__(256) void normalize(const float* __restrict__ mag,
                                                 float* __restrict__ feat)
{
    const int row = blockIdx.x * 4 + (threadIdx.x >> 6);    // b*NFREQ+f
    const int lane = threadIdx.x & 63;
    const float* mp = mag + (size_t)row * TFRAMES;

    float4 v[3];
    float sum = 0.f;
    #pragma unroll
    for (int i = 0; i < 3; i++) {
        int c4 = lane + i * 64;                 // 156 float4 per row
        if (c4 < TFRAMES / 4) {
            float4 t = *(const float4*)(mp + c4 * 4);
            t.x = fmaxf(t.x, EPS); t.y = fmaxf(t.y, EPS);
            t.z = fmaxf(t.z, EPS); t.w = fmaxf(t.w, EPS);
            v[i] = t;
            sum += (t.x + t.y) + (t.z + t.w);
        } else {
            v[i] = make_float4(0.f, 0.f, 0.f, 0.f);
        }
    }
    #pragma unroll
    for (int off = 1; off < 64; off <<= 1) sum += __shfl_xor(sum, off, 64);
    const float mean = sum * (1.0f / (float)TFRAMES);

    float ssd = 0.f;
    #pragma unroll
    for (int i = 0; i < 3; i++) {
        int c4 = lane + i * 64;
        if (c4 < TFRAMES / 4) {
            float dx = v[i].x - mean, dy = v[i].y - mean;
            float dz = v[i].z - mean, dw = v[i].w - mean;
            ssd += (dx * dx + dy * dy) + (dz * dz + dw * dw);
        }
    }
    #pragma unroll
    for (int off = 1; off < 64; off <<= 1) ssd += __shfl_xor(ssd, off, 64);
    const float stdv = sqrtf(ssd * (1.0f / (float)(TFRAMES - 1)));
    const float inv = 1.0f / (stdv + EPS);

    float* fp = feat + (size_t)row * TFRAMES;
    #pragma unroll
    for (int i = 0; i < 3; i++) {
        int c4 = lane + i * 64;
        if (c4 < TFRAMES / 4) {
            float4 o;
            o.x = (v[i].x - mean) * inv; o.y = (v[i].y - mean) * inv;
            o.z = (v[i].z - mean) * inv; o.w = (v[i].w - mean) * inv;
            *(float4*)(fp + c4 * 4) = o;
        }
    }
}

// ---------------------------------------------------------------- launch ----
extern "C" void kernel_launch(void* const* d_in, const int* in_sizes, int n_in,
                              void* d_out, int out_size, void* d_ws, size_t ws_size,
                              hipStream_t stream) {
    const float* x = (const float*)d_in[0];
    unsigned short* Wt = (unsigned short*)d_ws;             // fragment tables
    unsigned short* xq = Wt + WT_TOTAL;                     // 4 x [64][40000]
    float* mag  = (float*)d_out;                            // [64][257][624]
    float* feat = mag + (size_t)NBATCH * NFREQ * TFRAMES;

    prep<<<TBLKS + XBLKS, 256, 0, stream>>>(x, xq, Wt);

    // 312 M-tiles x 3 F-tiles, linearized + XCD-swizzled in-kernel
    stft_mfma<<<312 * 3, 256, 0, stream>>>(xq, Wt, mag);

    normalize<<<NBATCH * NFREQ / 4, 256, 0, stream>>>(mag, feat);
}

// Round 18
// 51.800 us; speedup vs baseline: 1.1657x; 1.1657x over previous
//
#include <hip/hip_runtime.h>
#include <math.h>

#define FRAME_LEN 512
#define HOP       256
#define NFREQ     257
#define NBATCH    64
#define NSAMP     160000
#define NSQ       40000        // samples per residue per batch
#define TFRAMES   624
#define EPS       1.1920928955078125e-07f

#define MT 128                 // frames per tile; 312 M-tiles
#define FT 32                  // freq bins per tile; 3 f-tiles (f 0..64 pad 96)
#define BK 64                  // k' chunk per stage
#define RS 2560000             // shorts per residue array (64*40000)
#define TS 12288               // shorts per table (96*128)
#define TBLKS 96
#define XBLKS 2500             // x blocks: 16 f32/thread

#define ASZ (MT * BK)          // shorts per A buffer (8192)
#define BSZ (2 * FT * BK)      // shorts per B buffer (4096)

typedef __attribute__((ext_vector_type(8))) short short8;   // 8 bf16
typedef __attribute__((ext_vector_type(4))) float f32x4;    // MFMA acc

static __device__ __forceinline__ unsigned int f2bf(float f) {
    unsigned int u = __float_as_uint(f);
    return (u + 0x7fffu + ((u >> 16) & 1u)) >> 16;          // RNE to bf16
}
static __device__ __forceinline__ void gload_lds16(const void* g, void* l) {
    __builtin_amdgcn_global_load_lds(
        (const __attribute__((address_space(1))) void*)g,
        (__attribute__((address_space(3))) void*)l, 16, 0, 0);
}

// ---- prep: tables W[r][cs][96][128] + x de-interleaved mod 4 -> xq[r] ------
__global__ __launch_bounds__(256) void prep(const float* __restrict__ x,
                                            unsigned short* __restrict__ xq,
                                            unsigned short* __restrict__ Wt) {
    if (blockIdx.x < TBLKS) {                   // tables; f<=64 live, rest 0
        const int f = blockIdx.x;               // 0..95
        #pragma unroll
        for (int h = 0; h < 2; h++) {
            const int n = threadIdx.x + h * 256;        // 0..511
            unsigned short cb = 0, sb = 0;
            if (f <= 64) {
                float w = 0.5f * (1.0f - cosf(2.0f * (float)M_PI * (float)n / (float)FRAME_LEN));
                float ang = (float)((f * n) & (FRAME_LEN - 1)) * (2.0f * (float)M_PI / (float)FRAME_LEN);
                float sv, cv;
                sincosf(ang, &sv, &cv);
                cb = (unsigned short)f2bf(cv * w);
                sb = (unsigned short)f2bf(sv * w);      // i = +sin convention
            }
            const int r = n & 3, q = n >> 2;
            Wt[(r * 2 + 0) * TS + f * 128 + q] = cb;
            Wt[(r * 2 + 1) * TS + f * 128 + q] = sb;
        }
    } else {                                    // 16 f32/thread, mod-4 split
        const int i = (blockIdx.x - TBLKS) * 256 + threadIdx.x;
        const int g = i * 16;
        const int b = g / NSAMP;
        const int s = g - b * NSAMP;            // 160000%16==0: one batch
        const float4* src = (const float4*)(x + (size_t)b * NSAMP + s);
        const float4 v0 = src[0], v1 = src[1], v2 = src[2], v3 = src[3];
        const size_t o = (size_t)b * NSQ + (s >> 2);
        uint2 p;
        p.x = f2bf(v0.x) | (f2bf(v1.x) << 16);
        p.y = f2bf(v2.x) | (f2bf(v3.x) << 16);
        *(uint2*)(xq + 0 * (size_t)RS + o) = p;
        p.x = f2bf(v0.y) | (f2bf(v1.y) << 16);
        p.y = f2bf(v2.y) | (f2bf(v3.y) << 16);
        *(uint2*)(xq + 1 * (size_t)RS + o) = p;
        p.x = f2bf(v0.z) | (f2bf(v1.z) << 16);
        p.y = f2bf(v2.z) | (f2bf(v3.z) << 16);
        *(uint2*)(xq + 2 * (size_t)RS + o) = p;
        p.x = f2bf(v0.w) | (f2bf(v1.w) << 16);
        p.y = f2bf(v2.w) | (f2bf(v3.w) << 16);
        *(uint2*)(xq + 3 * (size_t)RS + o) = p;
    }
}

// ---- stft: radix-4 symmetry — r10 inner loop, 4-bin epilogue ---------------
__global__ __launch_bounds__(256) void stft_mfma(
    const unsigned short* __restrict__ xq, const unsigned short* __restrict__ Wt,
    float* __restrict__ mag)
{
    __shared__ unsigned short As[2][MT][BK];    // 32 KB, linear gload dest
    __shared__ unsigned short Bs[2][2][FT][BK]; // 16 KB (cos, sin)

    const int tid = threadIdx.x;
    // XCD swizzle: nwg=936=8*117; 3 consecutive logicals share an A-tile.
    const int logical = ((int)blockIdx.x & 7) * 117 + ((int)blockIdx.x >> 3);
    const int tileM = logical / 3;              // 0..311
    const int tileF = logical % 3;              // 0..2
    const int wid = tid >> 6;
    const int lane = tid & 63;
    const int lrow = lane & 15;
    const int lhi = lane >> 4;

    unsigned short* AsB = &As[0][0][0];
    unsigned short* BsB = &Bs[0][0][0][0];

    // residue-0 staging sources (XOR chunk swizzle on SOURCE; dest linear);
    // residue r / k-chunk kc add the compile-time constant r*RS + kc*64.
    const unsigned short* pA[4];
    #pragma unroll
    for (int j = 0; j < 4; j++) {
        int idx = wid * 4 + j;                  // 0..15, 8 rows each
        int row = idx * 8 + (lane >> 3);
        int m = tileM * MT + row;               // < 39936 exact
        int b = m / TFRAMES;
        int t = m - b * TFRAMES;
        int chunk = (lane & 7) ^ (row & 7);
        pA[j] = xq + (size_t)b * NSQ + t * (HOP / 4) + chunk * 8;
    }
    const unsigned short* pB[2];
    #pragma unroll
    for (int j = 0; j < 2; j++) {
        int i = wid * 2 + j;                    // 0..7: 0-3 cos, 4-7 sin
        int row = (i & 3) * 8 + (lane >> 3);
        int fg = tileF * FT + row;              // < 96 (padded tables)
        int chunk = (lane & 7) ^ (row & 7);
        pB[j] = Wt + ((i & 4) ? TS : 0) + fg * 128 + chunk * 8;
    }

    f32x4 aC[4][2][2] = {};                     // [residue][mf][nf]
    f32x4 aS[4][2][2] = {};

    // ---- prologue: stage (residue 0, kc 0) into buf 0
    #pragma unroll
    for (int j = 0; j < 4; j++)
        gload_lds16(pA[j], AsB + (wid * 4 + j) * 512);
    #pragma unroll
    for (int j = 0; j < 2; j++)
        gload_lds16(pB[j], BsB + (wid * 2 + j) * 512);
    __syncthreads();

    int buf = 0;
    #pragma unroll
    for (int it = 0; it < 8; it++) {
        const int R = it >> 1;                  // residue (compile-time)
        // ---- stage next (residue, chunk) into other buffer
        if (it < 7) {
            const int Rn = (it + 1) >> 1;
            const int kn = ((it + 1) & 1) * BK;
            const size_t aoff = (size_t)Rn * RS + kn;
            const size_t boff = (size_t)Rn * (2 * TS) + kn;
            #pragma unroll
            for (int j = 0; j < 4; j++)
                gload_lds16(pA[j] + aoff, AsB + (buf ^ 1) * ASZ + (wid * 4 + j) * 512);
            #pragma unroll
            for (int j = 0; j < 2; j++)
                gload_lds16(pB[j] + boff, BsB + (buf ^ 1) * BSZ + (wid * 2 + j) * 512);
        }
        // ---- compute current buffer into residue-R accumulators
        #pragma unroll
        for (int ks = 0; ks < 2; ks++) {
            short8 a[2], bc[2], bsn[2];
            const int c = (ks * 4 + lhi) ^ (lrow & 7);
            #pragma unroll
            for (int mf = 0; mf < 2; mf++)
                a[mf] = *(const short8*)(AsB + buf * ASZ +
                    (wid * 32 + mf * 16 + lrow) * BK + c * 8);
            #pragma unroll
            for (int nf = 0; nf < 2; nf++) {
                bc[nf]  = *(const short8*)(BsB + buf * BSZ +
                    (nf * 16 + lrow) * BK + c * 8);
                bsn[nf] = *(const short8*)(BsB + buf * BSZ + FT * BK +
                    (nf * 16 + lrow) * BK + c * 8);
            }
            #pragma unroll
            for (int mf = 0; mf < 2; mf++) {
                #pragma unroll
                for (int nf = 0; nf < 2; nf++) {
                    aC[R][mf][nf] = __builtin_amdgcn_mfma_f32_16x16x32_bf16(
                        a[mf], bc[nf], aC[R][mf][nf], 0, 0, 0);
                    aS[R][mf][nf] = __builtin_amdgcn_mfma_f32_16x16x32_bf16(
                        a[mf], bsn[nf], aS[R][mf][nf], 0, 0, 0);
                }
            }
        }
        __syncthreads();                        // next buffer landed; reads done
        buf ^= 1;
    }

    // ---- epilogue: 4 bins per f<=64 via quarter-period sign combos
    #pragma unroll
    for (int mf = 0; mf < 2; mf++) {
        int m0 = tileM * MT + wid * 32 + mf * 16 + lhi * 4;
        int b = m0 / TFRAMES;
        int t = m0 - b * TFRAMES;               // %4==0, run stays in batch
        float* magb = mag + (size_t)b * NFREQ * TFRAMES + t;
        #pragma unroll
        for (int nf = 0; nf < 2; nf++) {
            int f = tileF * FT + nf * 16 + lrow;    // 0..95
            float4 o1, o2, o3, o4;
            #pragma unroll
            for (int q = 0; q < 4; q++) {
                const float C0 = aC[0][mf][nf][q], C1 = aC[1][mf][nf][q];
                const float C2 = aC[2][mf][nf][q], C3 = aC[3][mf][nf][q];
                const float S0 = aS[0][mf][nf][q], S1 = aS[1][mf][nf][q];
                const float S2 = aS[2][mf][nf][q], S3 = aS[3][mf][nf][q];
                float r, i2;
                r = (C0 + C2) + (C1 + C3); i2 = (S0 + S2) + (S1 + S3);  // f
                (&o1.x)[q] = sqrtf(r * r + i2 * i2);
                r = (C0 - C2) + (S1 - S3); i2 = (C1 - C3) - (S0 - S2);  // 128-f
                (&o2.x)[q] = sqrtf(r * r + i2 * i2);
                r = (C0 - C2) - (S1 - S3); i2 = (C1 - C3) + (S0 - S2);  // 128+f
                (&o3.x)[q] = sqrtf(r * r + i2 * i2);
                r = (C0 + C2) - (C1 + C3); i2 = (S1 + S3) - (S0 + S2);  // 256-f
                (&o4.x)[q] = sqrtf(r * r + i2 * i2);
            }
            if (f <= 64)           *(float4*)(magb + (size_t)f * TFRAMES) = o1;
            if (f <= 63)           *(float4*)(magb + (size_t)(128 - f) * TFRAMES) = o2;
            if (f >= 1 && f <= 64) *(float4*)(magb + (size_t)(128 + f) * TFRAMES) = o3;
            if (f <= 63)           *(float4*)(magb + (size_t)(256 - f) * TFRAMES) = o4;
        }
    }
}

// ------------------------------------------- normalize: warp-per-row, f4 ----
__global__ __launch_bounds__(256) void normalize(const float* __restrict__ mag,
                                                 float* __restrict__ feat)
{
    const int row = blockIdx.x * 4 + (threadIdx.x >> 6);    // b*NFREQ+f
    const int lane = threadIdx.x & 63;
    const float* mp = mag + (size_t)row * TFRAMES;

    float4 v[3];
    float sum = 0.f;
    #pragma unroll
    for (int i = 0; i < 3; i++) {
        int c4 = lane + i * 64;                 // 156 float4 per row
        if (c4 < TFRAMES / 4) {
            float4 t = *(const float4*)(mp + c4 * 4);
            t.x = fmaxf(t.x, EPS); t.y = fmaxf(t.y, EPS);
            t.z = fmaxf(t.z, EPS); t.w = fmaxf(t.w, EPS);
            v[i] = t;
            sum += (t.x + t.y) + (t.z + t.w);
        } else {
            v[i] = make_float4(0.f, 0.f, 0.f, 0.f);
        }
    }
    #pragma unroll
    for (int off = 1; off < 64; off <<= 1) sum += __shfl_xor(sum, off, 64);
    const float mean = sum * (1.0f / (float)TFRAMES);

    float ssd = 0.f;
    #pragma unroll
    for (int i = 0; i < 3; i++) {
        int c4 = lane + i * 64;
        if (c4 < TFRAMES / 4) {
            float dx = v[i].x - mean, dy = v[i].y - mean;
            float dz = v[i].z - mean, dw = v[i].w - mean;
            ssd += (dx * dx + dy * dy) + (dz * dz + dw * dw);
        }
    }
    #pragma unroll
    for (int off = 1; off < 64; off <<= 1) ssd += __shfl_xor(ssd, off, 64);
    const float stdv = sqrtf(ssd * (1.0f / (float)(TFRAMES - 1)));
    const float inv = 1.0f / (stdv + EPS);

    float* fp = feat + (size_t)row * TFRAMES;
    #pragma unroll
    for (int i = 0; i < 3; i++) {
        int c4 = lane + i * 64;
        if (c4 < TFRAMES / 4) {
            float4 o;
            o.x = (v[i].x - mean) * inv; o.y = (v[i].y - mean) * inv;
            o.z = (v[i].z - mean) * inv; o.w = (v[i].w - mean) * inv;
            *(float4*)(fp + c4 * 4) = o;
        }
    }
}

// ---------------------------------------------------------------- launch ----
extern "C" void kernel_launch(void* const* d_in, const int* in_sizes, int n_in,
                              void* d_out, int out_size, void* d_ws, size_t ws_size,
                              hipStream_t stream) {
    const float* x = (const float*)d_in[0];
    unsigned short* Wt = (unsigned short*)d_ws;             // 8 tables [96][128]
    unsigned short* xq = Wt + 8 * TS;                       // 4 x [64][40000]
    float* mag  = (float*)d_out;                            // [64][257][624]
    float* feat = mag + (size_t)NBATCH * NFREQ * TFRAMES;

    prep<<<TBLKS + XBLKS, 256, 0, stream>>>(x, xq, Wt);

    // 312 M-tiles x 3 F-tiles, linearized + XCD-swizzled in-kernel
    stft_mfma<<<312 * 3, 256, 0, stream>>>(xq, Wt, mag);

    normalize<<<NBATCH * NFREQ / 4, 256, 0, stream>>>(mag, feat);
}